// Round 4
// baseline (941.751 us; speedup 1.0000x reference)
//
#include <hip/hip_runtime.h>
#include <hip/hip_bf16.h>
#include <math.h>

// Problem constants (reference shapes are fixed)
#define NL   6
#define HD   512
#define NHD  8
#define DK   64
#define DFFN 1024
#define NB   8
#define TT   512
#define MROWS (NB*TT)   // 4096

typedef __hip_bfloat16 bf16;
typedef __attribute__((ext_vector_type(8))) short short8v;
typedef __attribute__((ext_vector_type(4))) float f32x4;

__device__ __forceinline__ float wave_sum(float v) {
#pragma unroll
  for (int off = 32; off; off >>= 1) v += __shfl_xor(v, off);
  return v;
}
__device__ __forceinline__ unsigned short f2bf(float x) {
  __hip_bfloat16 h = __float2bfloat16(x);
  return *reinterpret_cast<unsigned short*>(&h);
}

// global -> LDS async 16B (per-lane global addr, wave-linear LDS dest)
__device__ __forceinline__ void gload16(const void* g, void* l) {
  __builtin_amdgcn_global_load_lds(
      (const __attribute__((address_space(1))) unsigned int*)g,
      (__attribute__((address_space(3))) unsigned int*)l, 16, 0, 0);
}

// ---------------------------------------------------------------------------
// Weight prep: f32 [L][Kd][Nd] -> bf16 [L slab][dstRowOff+Nd][Kd] (transpose+convert)
__global__ __launch_bounds__(256)
void wprep_kernel(const float* __restrict__ W, bf16* __restrict__ Wt, int Kd, int Nd,
                  int dstRowOff, int dstSlabRows) {
  __shared__ float t[32][33];
  const size_t src = (size_t)blockIdx.z * Kd * Nd;
  const size_t dst = (size_t)blockIdx.z * dstSlabRows * Kd;
  const int n0 = blockIdx.x * 32, k0 = blockIdx.y * 32;
  const int tx = threadIdx.x & 31, ty = threadIdx.x >> 5;
#pragma unroll
  for (int j = 0; j < 4; ++j)
    t[ty + j * 8][tx] = W[src + (size_t)(k0 + ty + j * 8) * Nd + n0 + tx];
  __syncthreads();
#pragma unroll
  for (int j = 0; j < 4; ++j)
    Wt[dst + (size_t)(dstRowOff + n0 + ty + j * 8) * Kd + k0 + tx] =
        __float2bfloat16(t[tx][ty + j * 8]);
}

// bias concat: out[l][seg*512+off] = bseg[l][off], nseg segments of 512
__global__ __launch_bounds__(256)
void bcat_kernel(const float* __restrict__ b0, const float* __restrict__ b1,
                 const float* __restrict__ b2, float* __restrict__ out, int nseg) {
  const int l = blockIdx.x;
  const int stride = 512 * nseg;
  for (int i = threadIdx.x; i < stride; i += 256) {
    const int seg = i >> 9, off = i & 511;
    const float* src = seg == 0 ? b0 : (seg == 1 ? b1 : b2);
    out[(size_t)l * stride + i] = src[(size_t)l * 512 + off];
  }
}

// f32 -> bf16 elementwise, 4 per thread
__global__ __launch_bounds__(256)
void cvtbf16_kernel(const float* __restrict__ in, unsigned short* __restrict__ out) {
  const int i = (blockIdx.x * 256 + threadIdx.x) * 4;
  float4 v = *(const float4*)(in + i);
  out[i + 0] = f2bf(v.x); out[i + 1] = f2bf(v.y);
  out[i + 2] = f2bf(v.z); out[i + 3] = f2bf(v.w);
}

// ---------------------------------------------------------------------------
// Embedding + sinusoidal PE; writes f32 x and bf16 xb
__global__ __launch_bounds__(256)
void embed_pe_kernel(const int* __restrict__ idx, const float* __restrict__ emb,
                     float* __restrict__ x, unsigned short* __restrict__ xb) {
  const int row = blockIdx.x;
  const int t = row & (TT - 1);
  const int tok = idx[row];
  const float cdiv = -0.017988946009466842f;  // -ln(10000)/512
#pragma unroll
  for (int e0 = 0; e0 < 2; ++e0) {
    const int e = threadIdx.x + e0 * 256;
    const float div = __expf((float)(e & ~1) * cdiv);
    const float ang = (float)t * div;
    const float pe = (e & 1) ? cosf(ang) : sinf(ang);
    const float v = emb[(size_t)tok * HD + e] + pe;
    x[(size_t)row * HD + e] = v;
    xb[(size_t)row * HD + e] = f2bf(v);
  }
}

// ---------------------------------------------------------------------------
// bf16 MFMA GEMM v2: C[M,N] = A[M,K] @ Bt[N,K]^T + bias[N]
// 128xTN tile (TN=128 or 64), 4 waves (2x2), wave computes 64x(TN/2).
// Staging: global_load_lds dwordx4, double-buffered LDS, prefetch in flight
// across compute. XOR swizzle via inverse-swizzled GLOBAL source (rule #21):
// LDS(row r, chunk s) holds global chunk s^(r&7); read at chunk c^(r&7).
template<int TN, int OUT_BF16, int RELU>
__global__ __launch_bounds__(256)
void mgemm2_kernel(const bf16* __restrict__ A, const bf16* __restrict__ Bt,
                   const float* __restrict__ bias, float* __restrict__ Cf,
                   unsigned short* __restrict__ Cb, int M, int N, int K) {
  constexpr int NR = TN / 32;   // col frags per wave (4 or 2)
  constexpr int BJ = TN / 32;   // 8-row B segments staged per wave
  __shared__ __attribute__((aligned(16))) char As[2][128 * 128];
  __shared__ __attribute__((aligned(16))) char Bs[2][TN * 128];

  const int tid = threadIdx.x, w = tid >> 6, lane = tid & 63;
  const int wm = w >> 1, wn = w & 1;
  const int m0 = blockIdx.x * 128, n0 = blockIdx.y * TN;
  const int lrow = lane >> 3;              // 0..7 row within 8-row segment
  const int lchk = (lane & 7) ^ lrow;      // inverse-swizzled source chunk

  const bf16* ga[4];
#pragma unroll
  for (int j = 0; j < 4; ++j)
    ga[j] = A + (size_t)(m0 + w * 32 + j * 8 + lrow) * K + lchk * 8;
  const bf16* gb[BJ];
#pragma unroll
  for (int j = 0; j < BJ; ++j)
    gb[j] = Bt + (size_t)(n0 + w * (8 * BJ) + j * 8 + lrow) * K + lchk * 8;

  f32x4 acc[4][NR];
#pragma unroll
  for (int fm = 0; fm < 4; ++fm)
#pragma unroll
    for (int fn = 0; fn < NR; ++fn) acc[fm][fn] = (f32x4){0.f, 0.f, 0.f, 0.f};

  const int l4 = lane & 15;
  const int khb = (lane >> 4) * 16;

  auto issue = [&](int t, int buf) {
#pragma unroll
    for (int j = 0; j < 4; ++j)
      gload16(ga[j] + t * 64, &As[buf][(w * 32 + j * 8) * 128]);
#pragma unroll
    for (int j = 0; j < BJ; ++j)
      gload16(gb[j] + t * 64, &Bs[buf][(w * (8 * BJ) + j * 8) * 128]);
  };
  auto compute = [&](int buf) {
#pragma unroll
    for (int kk = 0; kk < 2; ++kk) {
      short8v af[4], bfv[NR];
#pragma unroll
      for (int fm = 0; fm < 4; ++fm) {
        const int r = wm * 64 + fm * 16 + l4;
        af[fm] = *(const short8v*)(&As[buf][r * 128 + ((kk * 64 + khb) ^ ((r & 7) << 4))]);
      }
#pragma unroll
      for (int fn = 0; fn < NR; ++fn) {
        const int r = wn * (TN / 2) + fn * 16 + l4;
        bfv[fn] = *(const short8v*)(&Bs[buf][r * 128 + ((kk * 64 + khb) ^ ((r & 7) << 4))]);
      }
#pragma unroll
      for (int fm = 0; fm < 4; ++fm)
#pragma unroll
        for (int fn = 0; fn < NR; ++fn)
          acc[fm][fn] = __builtin_amdgcn_mfma_f32_16x16x32_bf16(af[fm], bfv[fn], acc[fm][fn], 0, 0, 0);
    }
  };

  const int NT = K >> 6;
  issue(0, 0);
  for (int t = 0; t < NT; ++t) {
    __syncthreads();                    // drains vmcnt: tile t resident
    if (t + 1 < NT) issue(t + 1, (t + 1) & 1);  // in flight across compute
    compute(t & 1);
  }

  const int crow = (lane >> 4) * 4, ccol = l4;
#pragma unroll
  for (int fm = 0; fm < 4; ++fm)
#pragma unroll
    for (int fn = 0; fn < NR; ++fn) {
      const int gr = m0 + wm * 64 + fm * 16 + crow;
      const int gc = n0 + wn * (TN / 2) + fn * 16 + ccol;
      const float bs = bias[gc];
#pragma unroll
      for (int r = 0; r < 4; ++r) {
        float vv = acc[fm][fn][r] + bs;
        if (RELU) vv = fmaxf(vv, 0.f);
        if (OUT_BF16) Cb[(size_t)(gr + r) * N + gc] = f2bf(vv);
        else          Cf[(size_t)(gr + r) * N + gc] = vv;
      }
    }
}

// ---------------------------------------------------------------------------
// MFMA flash attention. Block = (b,h,64 q-rows), 4 waves x 16 q-rows.
// q/k/v pointers pre-offset to their column blocks; row strides passed.
template<int CAUSAL>
__global__ __launch_bounds__(256)
void mattn_kernel(const unsigned short* __restrict__ q, const unsigned short* __restrict__ kgl,
                  const unsigned short* __restrict__ vgl, unsigned short* __restrict__ ctx,
                  const int* __restrict__ idx, const unsigned char* __restrict__ emask,
                  int qstride, int kvstride) {
  __shared__ __attribute__((aligned(16))) unsigned short kt[64 * 64];   // [key][d] swz
  __shared__ __attribute__((aligned(16))) unsigned short vt[64 * 64];   // [d][key] swz
  __shared__ __attribute__((aligned(16))) unsigned short pl[4][16 * 64];// per-wave P swz
  __shared__ float km[64];

  const int bh = blockIdx.x;
  const int b = bh >> 3, h = bh & 7;
  const int qbase = blockIdx.y * 64;
  const int tid = threadIdx.x, w = tid >> 6, lane = tid & 63;
  const int l4 = lane & 15, g = lane >> 4;

  const unsigned short* qp = q + (size_t)(b * TT + qbase + w * 16 + l4) * qstride + h * DK + g * 8;
  short8v aq0 = *(const short8v*)qp;
  short8v aq1 = *(const short8v*)(qp + 32);

  float m_r[4], l_r[4];
  f32x4 acc_o[4];
#pragma unroll
  for (int r = 0; r < 4; ++r) { m_r[r] = -1e30f; l_r[r] = 0.f; }
#pragma unroll
  for (int f = 0; f < 4; ++f) acc_o[f] = (f32x4){0.f, 0.f, 0.f, 0.f};

  const int kvEnd = CAUSAL ? (qbase + 64) : TT;
  for (int kt0 = 0; kt0 < kvEnd; kt0 += 64) {
    __syncthreads();
    if (tid < 64) {
      const int kp = b * TT + kt0 + tid;
      const bool mk = CAUSAL ? (idx[kp] == 0) : (emask[kp] != 0);
      km[tid] = mk ? 1.f : 0.f;
    }
    {
      const int r = tid >> 2;
      const int bc = (tid & 3) * 32;
      const unsigned short* kp = kgl + (size_t)(b * TT + kt0 + r) * kvstride + h * DK + (bc >> 1);
      short8v ka = *(const short8v*)kp;
      short8v kb2 = *(const short8v*)(kp + 8);
      const int sw = (r & 7) << 4;
      *(short8v*)((char*)kt + r * 128 + (bc ^ sw)) = ka;
      *(short8v*)((char*)kt + r * 128 + ((bc + 16) ^ sw)) = kb2;
    }
    {
      const int k2 = (tid & 31) * 2;
      const int d0 = (tid >> 5) * 8;
      const unsigned short* vp0 = vgl + (size_t)(b * TT + kt0 + k2) * kvstride + h * DK + d0;
      const unsigned short* vp1 = vp0 + kvstride;
      short8v v0 = *(const short8v*)vp0;
      short8v v1 = *(const short8v*)vp1;
#pragma unroll
      for (int j = 0; j < 8; ++j) {
        const int d = d0 + j;
        const unsigned pk = ((unsigned)(unsigned short)v0[j]) | (((unsigned)(unsigned short)v1[j]) << 16);
        *(unsigned*)((char*)vt + d * 128 + ((k2 * 2) ^ ((d & 7) << 4))) = pk;
      }
    }
    __syncthreads();

    f32x4 s4[4];
#pragma unroll
    for (int f = 0; f < 4; ++f) {
      const int krow = f * 16 + l4;
      const int sw = (krow & 7) << 4;
      short8v bk0 = *(const short8v*)((const char*)kt + krow * 128 + ((g * 16) ^ sw));
      short8v bk1 = *(const short8v*)((const char*)kt + krow * 128 + ((64 + g * 16) ^ sw));
      f32x4 a = {};
      a = __builtin_amdgcn_mfma_f32_16x16x32_bf16(aq0, bk0, a, 0, 0, 0);
      a = __builtin_amdgcn_mfma_f32_16x16x32_bf16(aq1, bk1, a, 0, 0, 0);
      s4[f] = a;
    }

    float sc_r[4];
#pragma unroll
    for (int r = 0; r < 4; ++r) {
      const int qpos = qbase + w * 16 + g * 4 + r;
      float sf[4];
#pragma unroll
      for (int f = 0; f < 4; ++f) {
        const int kpos = kt0 + f * 16 + l4;
        float s = s4[f][r] * 0.125f;
        const bool msk = (km[f * 16 + l4] != 0.f) || (CAUSAL && kpos > qpos);
        sf[f] = msk ? -1e9f : s;
      }
      float mx = fmaxf(fmaxf(sf[0], sf[1]), fmaxf(sf[2], sf[3]));
#pragma unroll
      for (int off = 8; off; off >>= 1) mx = fmaxf(mx, __shfl_xor(mx, off));
      const float mn = fmaxf(m_r[r], mx);
      const float sc = __expf(m_r[r] - mn);
      m_r[r] = mn;
      sc_r[r] = sc;
      float ps = 0.f;
      const int prow = g * 4 + r;
      const int psw = (prow & 7) << 4;
#pragma unroll
      for (int f = 0; f < 4; ++f) {
        const float p = __expf(sf[f] - mn);
        ps += p;
        *(unsigned short*)((char*)pl[w] + prow * 128 + ((f * 32 + l4 * 2) ^ psw)) = f2bf(p);
      }
#pragma unroll
      for (int off = 8; off; off >>= 1) ps += __shfl_xor(ps, off);
      l_r[r] = l_r[r] * sc + ps;
    }

#pragma unroll
    for (int f = 0; f < 4; ++f)
#pragma unroll
      for (int r = 0; r < 4; ++r) acc_o[f][r] *= sc_r[r];

    const int asw = (l4 & 7) << 4;
    short8v pa0 = *(const short8v*)((const char*)pl[w] + l4 * 128 + ((g * 16) ^ asw));
    short8v pa1 = *(const short8v*)((const char*)pl[w] + l4 * 128 + ((g * 16 + 64) ^ asw));
#pragma unroll
    for (int f = 0; f < 4; ++f) {
      const int drow = f * 16 + l4;
      const int sw = (drow & 7) << 4;
      short8v vb0 = *(const short8v*)((const char*)vt + drow * 128 + ((g * 16) ^ sw));
      short8v vb1 = *(const short8v*)((const char*)vt + drow * 128 + ((g * 16 + 64) ^ sw));
      acc_o[f] = __builtin_amdgcn_mfma_f32_16x16x32_bf16(pa0, vb0, acc_o[f], 0, 0, 0);
      acc_o[f] = __builtin_amdgcn_mfma_f32_16x16x32_bf16(pa1, vb1, acc_o[f], 0, 0, 0);
    }
  }

  float rl[4];
#pragma unroll
  for (int r = 0; r < 4; ++r) rl[r] = 1.f / l_r[r];
#pragma unroll
  for (int f = 0; f < 4; ++f)
#pragma unroll
    for (int r = 0; r < 4; ++r) {
      const int row = qbase + w * 16 + g * 4 + r;
      const int col = h * DK + f * 16 + l4;
      ctx[(size_t)(b * TT + row) * HD + col] = f2bf(acc_o[f][r] * rl[r]);
    }
}

// ---------------------------------------------------------------------------
// Fused residual-add + LayerNorm; writes f32 out and bf16 outb. out may alias res.
__global__ __launch_bounds__(256)
void ln_kernel(const float* __restrict__ y, const float* __restrict__ res,
               float* __restrict__ out, unsigned short* __restrict__ outb,
               const float* __restrict__ g, const float* __restrict__ bta) {
  const int row = blockIdx.x;
  const int tid = threadIdx.x;
  const int w = tid >> 6, lane = tid & 63;
  const float* yr = y + (size_t)row * HD;
  const float* rr = res + (size_t)row * HD;

  float v0 = yr[tid] + rr[tid];
  float v1 = yr[tid + 256] + rr[tid + 256];

  __shared__ float red[4];
  float s = wave_sum(v0 + v1);
  if (lane == 0) red[w] = s;
  __syncthreads();
  const float mean = (red[0] + red[1] + red[2] + red[3]) * (1.f / HD);
  __syncthreads();

  const float d0 = v0 - mean, d1 = v1 - mean;
  float qv = wave_sum(d0 * d0 + d1 * d1);
  if (lane == 0) red[w] = qv;
  __syncthreads();
  const float var = (red[0] + red[1] + red[2] + red[3]) * (1.f / HD);
  const float rstd = rsqrtf(var + 1e-5f);

  const float o0 = d0 * rstd * g[tid] + bta[tid];
  const float o1 = d1 * rstd * g[tid + 256] + bta[tid + 256];
  out[(size_t)row * HD + tid] = o0;
  out[(size_t)row * HD + tid + 256] = o1;
  outb[(size_t)row * HD + tid] = f2bf(o0);
  outb[(size_t)row * HD + tid + 256] = f2bf(o1);
}

// ---------------------------------------------------------------------------
extern "C" void kernel_launch(void* const* d_in, const int* in_sizes, int n_in,
                              void* d_out, int out_size, void* d_ws, size_t ws_size,
                              hipStream_t stream) {
  const int* idx = (const int*)d_in[0];
  const float* enc = (const float*)d_in[1];
  const unsigned char* emask = (const unsigned char*)d_in[2];
  const float* emb = (const float*)d_in[4];
  const float* sa_wq = (const float*)d_in[5];
  const float* sa_bq = (const float*)d_in[6];
  const float* sa_wk = (const float*)d_in[7];
  const float* sa_bk = (const float*)d_in[8];
  const float* sa_wv = (const float*)d_in[9];
  const float* sa_bv = (const float*)d_in[10];
  const float* sa_wo = (const float*)d_in[11];
  const float* sa_bo = (const float*)d_in[12];
  const float* ln1g = (const float*)d_in[13];
  const float* ln1b = (const float*)d_in[14];
  const float* ea_wq = (const float*)d_in[15];
  const float* ea_bq = (const float*)d_in[16];
  const float* ea_wk = (const float*)d_in[17];
  const float* ea_bk = (const float*)d_in[18];
  const float* ea_wv = (const float*)d_in[19];
  const float* ea_bv = (const float*)d_in[20];
  const float* ea_wo = (const float*)d_in[21];
  const float* ea_bo = (const float*)d_in[22];
  const float* ln2g = (const float*)d_in[23];
  const float* ln2b = (const float*)d_in[24];
  const float* c1w = (const float*)d_in[25];
  const float* c1b = (const float*)d_in[26];
  const float* c2w = (const float*)d_in[27];
  const float* c2b = (const float*)d_in[28];
  const float* ln3g = (const float*)d_in[29];
  const float* ln3b = (const float*)d_in[30];

  const size_t MH = (size_t)MROWS * HD;   // 2,097,152
  const size_t SQ = (size_t)HD * HD;      // 262,144
  char* ws = (char*)d_ws;
  float*          x    = (float*)(ws + 0);                    // 8 MB
  unsigned short* xb   = (unsigned short*)(ws + (8u << 20));  // 4 MB
  unsigned short* qkvb = (unsigned short*)(ws + (12u << 20)); // 12 MB [4096][1536]
  unsigned short* qcb  = (unsigned short*)(ws + (24u << 20)); // 4 MB [4096][512]
  unsigned short* kvb  = (unsigned short*)(ws + (28u << 20)); // 8 MB [4096][1024]
  unsigned short* cxb  = (unsigned short*)(ws + (36u << 20)); // 4 MB
  float*          yb   = (float*)(ws + (40u << 20));          // 8 MB
  unsigned short* encb = (unsigned short*)(ws + (48u << 20)); // 4 MB
  bf16*           wt   = (bf16*)(ws + (52u << 20));           // 37.75 MB
  float*          bcS  = (float*)(ws + (92u << 20));          // [6][1536]
  float*          bcKV = (float*)(ws + (93u << 20));          // [6][1024]
  unsigned short* hb   = qkvb;  // FFN hidden [4096][1024] aliases qkvb

  bf16* t_saqkv = wt;                          // [6][1536][512]
  bf16* t_sao   = wt + 18 * SQ;                // [6][512][512]
  bf16* t_eaq   = wt + 24 * SQ;                // [6][512][512]
  bf16* t_eakv  = wt + 30 * SQ;                // [6][1024][512]
  bf16* t_eao   = wt + 42 * SQ;                // [6][512][512]
  bf16* t_c1    = wt + 48 * SQ;                // [6][1024][512]
  bf16* t_c2    = wt + 60 * SQ;                // [6][512][1024]

  const dim3 blk(256);
  const dim3 gQKV(MROWS / 128, 1536 / 128);    // (32, 12)
  const dim3 g1024(MROWS / 128, 1024 / 128);   // (32, 8)
  const dim3 g512n(MROWS / 128, 512 / 64);     // (32, 8) TN=64
  const dim3 attng(NB * NHD, TT / 64);

  // ---- weight prep ----
  wprep_kernel<<<dim3(16, 16, NL), blk, 0, stream>>>(sa_wq, t_saqkv, HD, HD, 0, 1536);
  wprep_kernel<<<dim3(16, 16, NL), blk, 0, stream>>>(sa_wk, t_saqkv, HD, HD, 512, 1536);
  wprep_kernel<<<dim3(16, 16, NL), blk, 0, stream>>>(sa_wv, t_saqkv, HD, HD, 1024, 1536);
  wprep_kernel<<<dim3(16, 16, NL), blk, 0, stream>>>(sa_wo, t_sao, HD, HD, 0, 512);
  wprep_kernel<<<dim3(16, 16, NL), blk, 0, stream>>>(ea_wq, t_eaq, HD, HD, 0, 512);
  wprep_kernel<<<dim3(16, 16, NL), blk, 0, stream>>>(ea_wk, t_eakv, HD, HD, 0, 1024);
  wprep_kernel<<<dim3(16, 16, NL), blk, 0, stream>>>(ea_wv, t_eakv, HD, HD, 512, 1024);
  wprep_kernel<<<dim3(16, 16, NL), blk, 0, stream>>>(ea_wo, t_eao, HD, HD, 0, 512);
  wprep_kernel<<<dim3(32, 16, NL), blk, 0, stream>>>(c1w, t_c1, HD, DFFN, 0, 1024);
  wprep_kernel<<<dim3(16, 32, NL), blk, 0, stream>>>(c2w, t_c2, DFFN, HD, 0, 512);
  bcat_kernel<<<NL, blk, 0, stream>>>(sa_bq, sa_bk, sa_bv, bcS, 3);
  bcat_kernel<<<NL, blk, 0, stream>>>(ea_bk, ea_bv, nullptr, bcKV, 2);
  cvtbf16_kernel<<<MH / 1024, blk, 0, stream>>>(enc, encb);

  embed_pe_kernel<<<MROWS, blk, 0, stream>>>(idx, emb, x, xb);

  for (int l = 0; l < NL; ++l) {
    const size_t b512 = (size_t)l * HD;
    const size_t bFF = (size_t)l * DFFN;

    // ---- self attention ----
    mgemm2_kernel<128, 1, 0><<<gQKV, blk, 0, stream>>>(
        (const bf16*)xb, t_saqkv + (size_t)l * 3 * SQ, bcS + (size_t)l * 1536,
        nullptr, qkvb, MROWS, 1536, HD);
    mattn_kernel<1><<<attng, blk, 0, stream>>>(qkvb, qkvb + 512, qkvb + 1024, cxb,
                                               idx, emask, 1536, 1536);
    mgemm2_kernel<64, 0, 0><<<g512n, blk, 0, stream>>>(
        (const bf16*)cxb, t_sao + (size_t)l * SQ, sa_bo + b512, yb, nullptr, MROWS, HD, HD);
    ln_kernel<<<MROWS, blk, 0, stream>>>(yb, x, x, xb, ln1g + b512, ln1b + b512);

    // ---- cross attention ----
    mgemm2_kernel<64, 1, 0><<<g512n, blk, 0, stream>>>(
        (const bf16*)xb, t_eaq + (size_t)l * SQ, ea_bq + b512, nullptr, qcb, MROWS, HD, HD);
    mgemm2_kernel<128, 1, 0><<<g1024, blk, 0, stream>>>(
        (const bf16*)encb, t_eakv + (size_t)l * 2 * SQ, bcKV + (size_t)l * 1024,
        nullptr, kvb, MROWS, 1024, HD);
    mattn_kernel<0><<<attng, blk, 0, stream>>>(qcb, kvb, kvb + 512, cxb,
                                               idx, emask, 512, 1024);
    mgemm2_kernel<64, 0, 0><<<g512n, blk, 0, stream>>>(
        (const bf16*)cxb, t_eao + (size_t)l * SQ, ea_bo + b512, yb, nullptr, MROWS, HD, HD);
    ln_kernel<<<MROWS, blk, 0, stream>>>(yb, x, x, xb, ln2g + b512, ln2b + b512);

    // ---- FFN ----
    mgemm2_kernel<128, 1, 1><<<g1024, blk, 0, stream>>>(
        (const bf16*)xb, t_c1 + (size_t)l * 2 * SQ, c1b + bFF, nullptr, hb, MROWS, DFFN, HD);
    mgemm2_kernel<64, 0, 0><<<g512n, blk, 0, stream>>>(
        (const bf16*)hb, t_c2 + (size_t)l * 2 * SQ, c2b + b512, yb, nullptr, MROWS, HD, DFFN);
    ln_kernel<<<MROWS, blk, 0, stream>>>(yb, x, x, xb, ln3g + b512, ln3b + b512);
  }

  hipMemcpyAsync(d_out, x, MH * sizeof(float), hipMemcpyDeviceToDevice, stream);
}